// Round 10
// baseline (223.821 us; speedup 1.0000x reference)
//
#include <hip/hip_runtime.h>
#include <hip/hip_bf16.h>
#include <stdint.h>

#define B_ROWS 16384
#define NVARS 64
#define LAG 16
#define H1 64
#define H2 1024
#define KDIM (NVARS * H1)   // 4096

typedef __attribute__((ext_vector_type(8))) short short8;
typedef __attribute__((ext_vector_type(4))) short short4v;
typedef __attribute__((ext_vector_type(4))) float f32x4;

typedef __attribute__((address_space(3))) uint8_t lds_u8;
typedef const __attribute__((address_space(1))) uint8_t glob_u8;

__device__ __forceinline__ void gload_lds16(const void* g, void* l) {
    __builtin_amdgcn_global_load_lds((glob_u8*)g, (lds_u8*)l, 16, 0, 0);
}

__device__ __forceinline__ short f2bf_s(float x) {
    __hip_bfloat16 h = __float2bfloat16(x);
    return *(short*)&h;
}
__device__ __forceinline__ float bf_s2f(short s) {
    __hip_bfloat16 h = *(__hip_bfloat16*)&s;
    return __bfloat162float(h);
}

// ---------------------------------------------------------------------------
// Kernel 1 (run-once misc, one dispatch): W3 transpose / out init / W1,W2 prep
// ---------------------------------------------------------------------------
__global__ __launch_bounds__(256) void misc_pre_kernel(
    const float* __restrict__ w3, const float* __restrict__ b4,
    const float* __restrict__ W1, const float* __restrict__ W2,
    __hip_bfloat16* __restrict__ w3t, float* __restrict__ out,
    short* __restrict__ w1bh, short* __restrict__ w1bl,
    short* __restrict__ w2bh, short* __restrict__ w2bl) {
    __shared__ float tile[64][65];
    const int bid = blockIdx.x;
    const int t = threadIdx.x;

    if (bid < 1024) {
        const int k0 = (bid >> 4) * 64;
        const int n0 = (bid & 15) * 64;
        const int c = t & 63, r0 = t >> 6;
#pragma unroll
        for (int i = 0; i < 16; i++) {
            int r = r0 + i * 4;
            tile[r][c] = w3[(size_t)(k0 + r) * H2 + n0 + c];
        }
        __syncthreads();
#pragma unroll
        for (int i = 0; i < 16; i++) {
            int nr = r0 + i * 4;
            w3t[(size_t)(n0 + nr) * KDIM + k0 + c] = __float2bfloat16(tile[c][nr]);
        }
        return;
    }
    if (bid < 1088) {
        out[(bid - 1024) * 256 + t] = b4[0];
        return;
    }

    const int v = bid - 1088;
    for (int idx = t; idx < 64 * 32; idx += 256) {
        int col = idx >> 5, k = idx & 31;
        float wv = W1[((size_t)v * LAG + (k & 15)) * H1 + col];
        short hi = f2bf_s(wv);
        w1bh[((size_t)v * 64 + col) * 40 + k] = hi;
        w1bl[((size_t)v * 64 + col) * 40 + k] = (k < 16) ? f2bf_s(wv - bf_s2f(hi)) : (short)0;
    }
    for (int idx = t; idx < 64 * 64; idx += 256) {
        int col = idx >> 6, k = idx & 63;
        float wv = W2[((size_t)v * H1 + k) * H1 + col];
        short hi = f2bf_s(wv);
        w2bh[((size_t)v * 64 + col) * 72 + k] = hi;
        w2bl[((size_t)v * 64 + col) * 72 + k] = f2bf_s(wv - bf_s2f(hi));
    }
}

// ---------------------------------------------------------------------------
// Kernel 2: per-variable 2-layer subnet via split-bf16 MFMA (r8-validated).
// ---------------------------------------------------------------------------
__global__ __launch_bounds__(256) void subnets_mfma_kernel(
    const float* __restrict__ inputs, const float* __restrict__ b1g,
    const float* __restrict__ b2g, const float* __restrict__ impg,
    const short* __restrict__ w1bh_g, const short* __restrict__ w1bl_g,
    const short* __restrict__ w2bh_g, const short* __restrict__ w2bl_g,
    __hip_bfloat16* __restrict__ agg) {
    const int v = blockIdx.x >> 7;
    const int b0 = (blockIdx.x & 127) * 128;
    const int t = threadIdx.x;
    const int lane = t & 63, wv = t >> 6;
    const int l15 = lane & 15, g = lane >> 4;

    __shared__ __align__(16) char smem[38912];
    short* xsS   = (short*)smem;
    short* w1bhS = (short*)(smem + 10240);
    short* w1blS = (short*)(smem + 15360);
    short* Hs    = (short*)smem;
    short* w2bhS = (short*)(smem + 20480);
    short* w2blS = (short*)(smem + 29696);

    for (int c = t; c < 320; c += 256) {
        gload_lds16(w1bh_g + (size_t)v * 2560 + c * 8, (char*)w1bhS + c * 16);
        gload_lds16(w1bl_g + (size_t)v * 2560 + c * 8, (char*)w1blS + c * 16);
    }
    for (int c = t; c < 576; c += 256) {
        gload_lds16(w2bh_g + (size_t)v * 4608 + c * 8, (char*)w2bhS + c * 16);
        gload_lds16(w2bl_g + (size_t)v * 4608 + c * 8, (char*)w2blS + c * 16);
    }
#pragma unroll
    for (int i = 0; i < 2; i++) {
        int idx = t + i * 256;
        int row = idx >> 2, seg = idx & 3;
        float4 x4 = *(const float4*)(inputs + (size_t)(b0 + row) * (NVARS * LAG) + v * LAG + seg * 4);
        const float* xp = (const float*)&x4;
        short4v hv, lv;
#pragma unroll
        for (int j = 0; j < 4; j++) {
            short hi = f2bf_s(xp[j]);
            hv[j] = hi;
            lv[j] = f2bf_s(xp[j] - bf_s2f(hi));
        }
        *(short4v*)&xsS[row * 40 + seg * 4] = hv;
        *(short4v*)&xsS[row * 40 + 16 + seg * 4] = lv;
    }
    __syncthreads();

    short8 a1[2], b1hF[4], b1lF[4];
#pragma unroll
    for (int mt = 0; mt < 2; mt++)
        a1[mt] = *(const short8*)&xsS[(wv * 32 + mt * 16 + l15) * 40 + g * 8];
#pragma unroll
    for (int nt = 0; nt < 4; nt++) {
        b1hF[nt] = *(const short8*)&w1bhS[(nt * 16 + l15) * 40 + g * 8];
        b1lF[nt] = *(const short8*)&w1blS[(nt * 16 + l15) * 40 + g * 8];
    }
    f32x4 acc1[2][4];
#pragma unroll
    for (int mt = 0; mt < 2; mt++)
#pragma unroll
        for (int nt = 0; nt < 4; nt++) {
            acc1[mt][nt] = (f32x4){0.f, 0.f, 0.f, 0.f};
            acc1[mt][nt] = __builtin_amdgcn_mfma_f32_16x16x32_bf16(a1[mt], b1hF[nt], acc1[mt][nt], 0, 0, 0);
            acc1[mt][nt] = __builtin_amdgcn_mfma_f32_16x16x32_bf16(a1[mt], b1lF[nt], acc1[mt][nt], 0, 0, 0);
        }
    __syncthreads();

#pragma unroll
    for (int mt = 0; mt < 2; mt++)
#pragma unroll
        for (int nt = 0; nt < 4; nt++) {
            int col = nt * 16 + l15;
            float bias = b1g[v * H1 + col];
#pragma unroll
            for (int r = 0; r < 4; r++) {
                float h = fmaxf(acc1[mt][nt][r] + bias, 0.f);
                int row = wv * 32 + mt * 16 + g * 4 + r;
                Hs[row * 72 + col] = f2bf_s(h);
            }
        }
    __syncthreads();

    short8 a2[2][2], b2hF[4][2], b2lF[4][2];
#pragma unroll
    for (int mt = 0; mt < 2; mt++)
#pragma unroll
        for (int kc = 0; kc < 2; kc++)
            a2[mt][kc] = *(const short8*)&Hs[(wv * 32 + mt * 16 + l15) * 72 + kc * 32 + g * 8];
#pragma unroll
    for (int nt = 0; nt < 4; nt++)
#pragma unroll
        for (int kc = 0; kc < 2; kc++) {
            b2hF[nt][kc] = *(const short8*)&w2bhS[(nt * 16 + l15) * 72 + kc * 32 + g * 8];
            b2lF[nt][kc] = *(const short8*)&w2blS[(nt * 16 + l15) * 72 + kc * 32 + g * 8];
        }
    f32x4 acc2[2][4];
#pragma unroll
    for (int mt = 0; mt < 2; mt++)
#pragma unroll
        for (int nt = 0; nt < 4; nt++) {
            f32x4 a = (f32x4){0.f, 0.f, 0.f, 0.f};
            a = __builtin_amdgcn_mfma_f32_16x16x32_bf16(a2[mt][0], b2hF[nt][0], a, 0, 0, 0);
            a = __builtin_amdgcn_mfma_f32_16x16x32_bf16(a2[mt][1], b2hF[nt][1], a, 0, 0, 0);
            a = __builtin_amdgcn_mfma_f32_16x16x32_bf16(a2[mt][0], b2lF[nt][0], a, 0, 0, 0);
            a = __builtin_amdgcn_mfma_f32_16x16x32_bf16(a2[mt][1], b2lF[nt][1], a, 0, 0, 0);
            acc2[mt][nt] = a;
        }

    const float impv = impg[v];
#pragma unroll
    for (int mt = 0; mt < 2; mt++)
#pragma unroll
        for (int nt = 0; nt < 4; nt++) {
            int col = nt * 16 + l15;
            float bias = b2g[v * H1 + col];
#pragma unroll
            for (int r = 0; r < 4; r++) {
                float o = fmaxf(acc2[mt][nt][r] + bias, 0.f) * impv;
                int row = b0 + wv * 32 + mt * 16 + g * 4 + r;
                agg[(size_t)row * KDIM + v * H1 + col] = __float2bfloat16(o);
            }
        }
}

// ---------------------------------------------------------------------------
// Kernel 3: relu(agg @ W3 + b3) . W4 -> atomicAdd into out.
// r10: A staged via global_load_lds (4 buffers, 64 KB, swizzled — r8 path);
// B read DIRECTLY global->VGPR (w3t is L2/L3-hot; frag pattern is a natural
// global access), double-buffered across tile parity, loaded one tile ahead
// (after the MFMAs that consume the same reg set — no in-tile hazard).
// vmcnt ledger (issue order per tile: A-stage[2] ... fb-load[4]):
//   end-of-tile queue = [A(tt+2):2, FB(tt+1):4, A(tt+3):2, FB(tt+2):4]
//   -> vmcnt(6) drains FB(tt+1) (+A(tt+2)); A-stage ~2 tiles in flight.
// Per-tile LDS: 8 ds_read_b128/wave (64 KB/CU) + 16 KB write < MFMA 1241cyc.
// ---------------------------------------------------------------------------
#define NT 128   // K-tiles of 32

__global__ __launch_bounds__(512, 2) void gemm3_kernel(
    const __hip_bfloat16* __restrict__ agg,   // [16384][4096]
    const __hip_bfloat16* __restrict__ w3t,   // [1024][4096]
    const float* __restrict__ b3, const float* __restrict__ W4,
    float* __restrict__ out) {
    const int bid = ((blockIdx.x & 7) << 5) + (blockIdx.x >> 3);   // T1 swizzle
    const int brow = (bid >> 2) * 256;
    const int bcol = (bid & 3) * 256;
    const int t = threadIdx.x;
    const int lane = t & 63;
    const int wid = t >> 6;                   // 8 waves
    const int wm = wid >> 2, wn = wid & 3;    // 2 x 4, wave tile 128x64
    const int l15 = lane & 15, g = lane >> 4;

    // LDS: 4 A-buffers of 16 KB
    __shared__ __align__(16) char smem[65536];

    // A staging: chunk c -> dest byte c*16 (linear); source col pre-swizzled
    const int c0 = t, c1 = t + 512;
    const int r0 = c0 >> 2, r1 = c1 >> 2;
    const int col0 = ((c0 & 3) * 8) ^ ((r0 & 8) ? 16 : 0);
    const int col1 = ((c1 & 3) * 8) ^ ((r1 & 8) ? 16 : 0);
    const __hip_bfloat16* aS0 = agg + (size_t)(brow + r0) * KDIM + col0;
    const __hip_bfloat16* aS1 = agg + (size_t)(brow + r1) * KDIM + col1;

#define STAGE_A(p, kt) do { \
        gload_lds16(aS0 + (kt) * 32, smem + (p) * 16384 + c0 * 16); \
        gload_lds16(aS1 + (kt) * 32, smem + (p) * 16384 + c1 * 16); } while (0)

    // swizzled A-fragment reads (row&8 == l15&8 for all m)
    const int coff = (g * 16) ^ ((l15 & 8) ? 32 : 0);
    const int aBase = (wm * 128 + l15) * 64 + coff;
#define LDA(i, p) fa[i] = *(const short8*)(smem + (p) * 16384 + aBase + (i) * 1024)

    // B fragments direct from global: fb[n] = w3t[bcol+wn*64+n*16+l15][kt*32+g*8..+8]
    const __hip_bfloat16* bP = w3t + (size_t)(bcol + wn * 64 + l15) * KDIM + g * 8;
#define LDFB(FB, kt) do { \
        FB[0] = *(const short8*)(bP + (size_t)(kt) * 32); \
        FB[1] = *(const short8*)(bP + (size_t)(kt) * 32 + 16 * KDIM); \
        FB[2] = *(const short8*)(bP + (size_t)(kt) * 32 + 32 * KDIM); \
        FB[3] = *(const short8*)(bP + (size_t)(kt) * 32 + 48 * KDIM); } while (0)

#define MM(FB) do { \
        __builtin_amdgcn_s_setprio(1); \
        _Pragma("unroll") \
        for (int mm = 0; mm < 8; mm++) \
            _Pragma("unroll") \
            for (int nn = 0; nn < 4; nn++) \
                acc[mm][nn] = __builtin_amdgcn_mfma_f32_16x16x32_bf16( \
                    fa[mm], FB[nn], acc[mm][nn], 0, 0, 0); \
        __builtin_amdgcn_s_setprio(0); } while (0)

    // TILE: stage A(kt3) early; ds-read fa; MFMA on FB (regs, loaded 2 tiles
    // ago); reload SAME FB set for tile tt+2 AFTER the MFMAs; vmcnt; barrier.
#define TILE(FB, p, DOSTAGE, kt3, DOFB, ktfb, VMSTR) do { \
        if (DOSTAGE) STAGE_A((kt3) & 3, kt3); \
        LDA(0, p); LDA(1, p); LDA(2, p); LDA(3, p); \
        LDA(4, p); LDA(5, p); LDA(6, p); LDA(7, p); \
        MM(FB); \
        if (DOFB) LDFB(FB, ktfb); \
        asm volatile(VMSTR ::: "memory"); \
        __builtin_amdgcn_s_barrier(); \
        __builtin_amdgcn_sched_barrier(0); } while (0)

    short8 fa[8], fb0[4], fb1[4];
    f32x4 acc[8][4];
#pragma unroll
    for (int m = 0; m < 8; m++)
#pragma unroll
        for (int n = 0; n < 4; n++) acc[m][n] = (f32x4){0.f, 0.f, 0.f, 0.f};

    // prologue: stage A tiles 0,1,2 (6 ops); load fb for tiles 0,1 (8 ops);
    // vmcnt(4) drains A0,A1,A2,FB0 (leaves FB1); barrier.
    STAGE_A(0, 0);
    STAGE_A(1, 1);
    STAGE_A(2, 2);
    LDFB(fb0, 0);
    LDFB(fb1, 1);
    asm volatile("s_waitcnt vmcnt(4)" ::: "memory");
    __builtin_amdgcn_s_barrier();
    __builtin_amdgcn_sched_barrier(0);

    // main loop: tiles 0..123 (62 pairs); p = tt&3 runtime (address math only)
    for (int t2 = 0; t2 < 62; ++t2) {
        const int tt = t2 * 2;
        TILE(fb0, tt & 3,       1, tt + 3, 1, tt + 2, "s_waitcnt vmcnt(6)");
        TILE(fb1, (tt + 1) & 3, 1, tt + 4, 1, tt + 3, "s_waitcnt vmcnt(6)");
    }
    // tail: 124 (stages A127, loads fb126), 125 (loads fb127), 126, 127
    TILE(fb0, 0, 1, 127, 1, 126, "s_waitcnt vmcnt(6)");
    TILE(fb1, 1, 0, 0,   1, 127, "s_waitcnt vmcnt(4)");
    TILE(fb0, 2, 0, 0,   0, 0,   "s_waitcnt vmcnt(0)");
    // tile 127: reads only, no barrier needed after
    LDA(0, 3); LDA(1, 3); LDA(2, 3); LDA(3, 3);
    LDA(4, 3); LDA(5, 3); LDA(6, 3); LDA(7, 3);
    MM(fb1);

    // epilogue: bias+relu, dot W4, 16-lane reduce, atomicAdd per row
    float bias[4], w4v[4];
#pragma unroll
    for (int n = 0; n < 4; n++) {
        int col = bcol + wn * 64 + n * 16 + l15;
        bias[n] = b3[col];
        w4v[n] = W4[col];
    }
#pragma unroll
    for (int m = 0; m < 8; m++) {
        float pr0 = 0.f, pr1 = 0.f, pr2 = 0.f, pr3 = 0.f;
#pragma unroll
        for (int n = 0; n < 4; n++) {
            pr0 += fmaxf(acc[m][n][0] + bias[n], 0.f) * w4v[n];
            pr1 += fmaxf(acc[m][n][1] + bias[n], 0.f) * w4v[n];
            pr2 += fmaxf(acc[m][n][2] + bias[n], 0.f) * w4v[n];
            pr3 += fmaxf(acc[m][n][3] + bias[n], 0.f) * w4v[n];
        }
#pragma unroll
        for (int mask = 1; mask < 16; mask <<= 1) {
            pr0 += __shfl_xor(pr0, mask, 64);
            pr1 += __shfl_xor(pr1, mask, 64);
            pr2 += __shfl_xor(pr2, mask, 64);
            pr3 += __shfl_xor(pr3, mask, 64);
        }
        if (l15 == 0) {
            int row = brow + wm * 128 + m * 16 + g * 4;
            atomicAdd(&out[row + 0], pr0);
            atomicAdd(&out[row + 1], pr1);
            atomicAdd(&out[row + 2], pr2);
            atomicAdd(&out[row + 3], pr3);
        }
    }
}

// ---------------------------------------------------------------------------
extern "C" void kernel_launch(void* const* d_in, const int* in_sizes, int n_in,
                              void* d_out, int out_size, void* d_ws, size_t ws_size,
                              hipStream_t stream) {
    const float* inputs = (const float*)d_in[0];
    const float* W1 = (const float*)d_in[1];
    const float* b1 = (const float*)d_in[2];
    const float* W2 = (const float*)d_in[3];
    const float* b2 = (const float*)d_in[4];
    const float* imp = (const float*)d_in[5];
    const float* W3 = (const float*)d_in[6];
    const float* b3 = (const float*)d_in[7];
    const float* W4 = (const float*)d_in[8];
    const float* b4 = (const float*)d_in[9];
    float* out = (float*)d_out;

    char* ws = (char*)d_ws;
    const size_t agg_bytes = (size_t)B_ROWS * KDIM * 2;        // 134 MB
    const size_t w3t_bytes = (size_t)H2 * KDIM * 2;            // 8.4 MB
    const size_t w1b_bytes = (size_t)NVARS * 64 * 40 * 2;
    const size_t w2b_bytes = (size_t)NVARS * 64 * 72 * 2;

    __hip_bfloat16* agg = (__hip_bfloat16*)ws;
    __hip_bfloat16* w3t = (__hip_bfloat16*)(ws + agg_bytes);
    short* w1bh = (short*)(ws + agg_bytes + w3t_bytes);
    short* w1bl = (short*)(ws + agg_bytes + w3t_bytes + w1b_bytes);
    short* w2bh = (short*)(ws + agg_bytes + w3t_bytes + 2 * w1b_bytes);
    short* w2bl = (short*)(ws + agg_bytes + w3t_bytes + 2 * w1b_bytes + w2b_bytes);

    hipLaunchKernelGGL(misc_pre_kernel, dim3(1152), dim3(256), 0, stream,
                       W3, b4, W1, W2, w3t, out, w1bh, w1bl, w2bh, w2bl);
    hipLaunchKernelGGL(subnets_mfma_kernel, dim3(NVARS * (B_ROWS / 128)), dim3(256), 0, stream,
                       inputs, b1, b2, imp, w1bh, w1bl, w2bh, w2bl, agg);
    hipLaunchKernelGGL(gemm3_kernel, dim3((B_ROWS / 256) * (H2 / 256)), dim3(512), 0, stream,
                       agg, w3t, b3, W4, out);
}

// Round 11
// 183.279 us; speedup vs baseline: 1.2212x; 1.2212x over previous
//
#include <hip/hip_runtime.h>
#include <hip/hip_bf16.h>
#include <stdint.h>

#define B_ROWS 16384
#define NVARS 64
#define LAG 16
#define H1 64
#define H2 1024
#define KDIM (NVARS * H1)   // 4096

typedef __attribute__((ext_vector_type(8))) short short8;
typedef __attribute__((ext_vector_type(4))) short short4v;
typedef __attribute__((ext_vector_type(4))) float f32x4;

typedef __attribute__((address_space(3))) uint8_t lds_u8;
typedef const __attribute__((address_space(1))) uint8_t glob_u8;

__device__ __forceinline__ void gload_lds16(const void* g, void* l) {
    __builtin_amdgcn_global_load_lds((glob_u8*)g, (lds_u8*)l, 16, 0, 0);
}

__device__ __forceinline__ short f2bf_s(float x) {
    __hip_bfloat16 h = __float2bfloat16(x);
    return *(short*)&h;
}
__device__ __forceinline__ float bf_s2f(short s) {
    __hip_bfloat16 h = *(__hip_bfloat16*)&s;
    return __bfloat162float(h);
}

// ---------------------------------------------------------------------------
// Kernel 1 (run-once misc, one dispatch): W3 transpose / out init / W1,W2 prep
// ---------------------------------------------------------------------------
__global__ __launch_bounds__(256) void misc_pre_kernel(
    const float* __restrict__ w3, const float* __restrict__ b4,
    const float* __restrict__ W1, const float* __restrict__ W2,
    __hip_bfloat16* __restrict__ w3t, float* __restrict__ out,
    short* __restrict__ w1bh, short* __restrict__ w1bl,
    short* __restrict__ w2bh, short* __restrict__ w2bl) {
    __shared__ float tile[64][65];
    const int bid = blockIdx.x;
    const int t = threadIdx.x;

    if (bid < 1024) {
        const int k0 = (bid >> 4) * 64;
        const int n0 = (bid & 15) * 64;
        const int c = t & 63, r0 = t >> 6;
#pragma unroll
        for (int i = 0; i < 16; i++) {
            int r = r0 + i * 4;
            tile[r][c] = w3[(size_t)(k0 + r) * H2 + n0 + c];
        }
        __syncthreads();
#pragma unroll
        for (int i = 0; i < 16; i++) {
            int nr = r0 + i * 4;
            w3t[(size_t)(n0 + nr) * KDIM + k0 + c] = __float2bfloat16(tile[c][nr]);
        }
        return;
    }
    if (bid < 1088) {
        out[(bid - 1024) * 256 + t] = b4[0];
        return;
    }

    const int v = bid - 1088;
    for (int idx = t; idx < 64 * 32; idx += 256) {
        int col = idx >> 5, k = idx & 31;
        float wv = W1[((size_t)v * LAG + (k & 15)) * H1 + col];
        short hi = f2bf_s(wv);
        w1bh[((size_t)v * 64 + col) * 40 + k] = hi;
        w1bl[((size_t)v * 64 + col) * 40 + k] = (k < 16) ? f2bf_s(wv - bf_s2f(hi)) : (short)0;
    }
    for (int idx = t; idx < 64 * 64; idx += 256) {
        int col = idx >> 6, k = idx & 63;
        float wv = W2[((size_t)v * H1 + k) * H1 + col];
        short hi = f2bf_s(wv);
        w2bh[((size_t)v * 64 + col) * 72 + k] = hi;
        w2bl[((size_t)v * 64 + col) * 72 + k] = f2bf_s(wv - bf_s2f(hi));
    }
}

// ---------------------------------------------------------------------------
// Kernel 2: per-variable 2-layer subnet via split-bf16 MFMA (r8-validated).
// ---------------------------------------------------------------------------
__global__ __launch_bounds__(256) void subnets_mfma_kernel(
    const float* __restrict__ inputs, const float* __restrict__ b1g,
    const float* __restrict__ b2g, const float* __restrict__ impg,
    const short* __restrict__ w1bh_g, const short* __restrict__ w1bl_g,
    const short* __restrict__ w2bh_g, const short* __restrict__ w2bl_g,
    __hip_bfloat16* __restrict__ agg) {
    const int v = blockIdx.x >> 7;
    const int b0 = (blockIdx.x & 127) * 128;
    const int t = threadIdx.x;
    const int lane = t & 63, wv = t >> 6;
    const int l15 = lane & 15, g = lane >> 4;

    __shared__ __align__(16) char smem[38912];
    short* xsS   = (short*)smem;
    short* w1bhS = (short*)(smem + 10240);
    short* w1blS = (short*)(smem + 15360);
    short* Hs    = (short*)smem;
    short* w2bhS = (short*)(smem + 20480);
    short* w2blS = (short*)(smem + 29696);

    for (int c = t; c < 320; c += 256) {
        gload_lds16(w1bh_g + (size_t)v * 2560 + c * 8, (char*)w1bhS + c * 16);
        gload_lds16(w1bl_g + (size_t)v * 2560 + c * 8, (char*)w1blS + c * 16);
    }
    for (int c = t; c < 576; c += 256) {
        gload_lds16(w2bh_g + (size_t)v * 4608 + c * 8, (char*)w2bhS + c * 16);
        gload_lds16(w2bl_g + (size_t)v * 4608 + c * 8, (char*)w2blS + c * 16);
    }
#pragma unroll
    for (int i = 0; i < 2; i++) {
        int idx = t + i * 256;
        int row = idx >> 2, seg = idx & 3;
        float4 x4 = *(const float4*)(inputs + (size_t)(b0 + row) * (NVARS * LAG) + v * LAG + seg * 4);
        const float* xp = (const float*)&x4;
        short4v hv, lv;
#pragma unroll
        for (int j = 0; j < 4; j++) {
            short hi = f2bf_s(xp[j]);
            hv[j] = hi;
            lv[j] = f2bf_s(xp[j] - bf_s2f(hi));
        }
        *(short4v*)&xsS[row * 40 + seg * 4] = hv;
        *(short4v*)&xsS[row * 40 + 16 + seg * 4] = lv;
    }
    __syncthreads();

    short8 a1[2], b1hF[4], b1lF[4];
#pragma unroll
    for (int mt = 0; mt < 2; mt++)
        a1[mt] = *(const short8*)&xsS[(wv * 32 + mt * 16 + l15) * 40 + g * 8];
#pragma unroll
    for (int nt = 0; nt < 4; nt++) {
        b1hF[nt] = *(const short8*)&w1bhS[(nt * 16 + l15) * 40 + g * 8];
        b1lF[nt] = *(const short8*)&w1blS[(nt * 16 + l15) * 40 + g * 8];
    }
    f32x4 acc1[2][4];
#pragma unroll
    for (int mt = 0; mt < 2; mt++)
#pragma unroll
        for (int nt = 0; nt < 4; nt++) {
            acc1[mt][nt] = (f32x4){0.f, 0.f, 0.f, 0.f};
            acc1[mt][nt] = __builtin_amdgcn_mfma_f32_16x16x32_bf16(a1[mt], b1hF[nt], acc1[mt][nt], 0, 0, 0);
            acc1[mt][nt] = __builtin_amdgcn_mfma_f32_16x16x32_bf16(a1[mt], b1lF[nt], acc1[mt][nt], 0, 0, 0);
        }
    __syncthreads();

#pragma unroll
    for (int mt = 0; mt < 2; mt++)
#pragma unroll
        for (int nt = 0; nt < 4; nt++) {
            int col = nt * 16 + l15;
            float bias = b1g[v * H1 + col];
#pragma unroll
            for (int r = 0; r < 4; r++) {
                float h = fmaxf(acc1[mt][nt][r] + bias, 0.f);
                int row = wv * 32 + mt * 16 + g * 4 + r;
                Hs[row * 72 + col] = f2bf_s(h);
            }
        }
    __syncthreads();

    short8 a2[2][2], b2hF[4][2], b2lF[4][2];
#pragma unroll
    for (int mt = 0; mt < 2; mt++)
#pragma unroll
        for (int kc = 0; kc < 2; kc++)
            a2[mt][kc] = *(const short8*)&Hs[(wv * 32 + mt * 16 + l15) * 72 + kc * 32 + g * 8];
#pragma unroll
    for (int nt = 0; nt < 4; nt++)
#pragma unroll
        for (int kc = 0; kc < 2; kc++) {
            b2hF[nt][kc] = *(const short8*)&w2bhS[(nt * 16 + l15) * 72 + kc * 32 + g * 8];
            b2lF[nt][kc] = *(const short8*)&w2blS[(nt * 16 + l15) * 72 + kc * 32 + g * 8];
        }
    f32x4 acc2[2][4];
#pragma unroll
    for (int mt = 0; mt < 2; mt++)
#pragma unroll
        for (int nt = 0; nt < 4; nt++) {
            f32x4 a = (f32x4){0.f, 0.f, 0.f, 0.f};
            a = __builtin_amdgcn_mfma_f32_16x16x32_bf16(a2[mt][0], b2hF[nt][0], a, 0, 0, 0);
            a = __builtin_amdgcn_mfma_f32_16x16x32_bf16(a2[mt][1], b2hF[nt][1], a, 0, 0, 0);
            a = __builtin_amdgcn_mfma_f32_16x16x32_bf16(a2[mt][0], b2lF[nt][0], a, 0, 0, 0);
            a = __builtin_amdgcn_mfma_f32_16x16x32_bf16(a2[mt][1], b2lF[nt][1], a, 0, 0, 0);
            acc2[mt][nt] = a;
        }

    const float impv = impg[v];
#pragma unroll
    for (int mt = 0; mt < 2; mt++)
#pragma unroll
        for (int nt = 0; nt < 4; nt++) {
            int col = nt * 16 + l15;
            float bias = b2g[v * H1 + col];
#pragma unroll
            for (int r = 0; r < 4; r++) {
                float o = fmaxf(acc2[mt][nt][r] + bias, 0.f) * impv;
                int row = b0 + wv * 32 + mt * 16 + g * 4 + r;
                agg[(size_t)row * KDIM + v * H1 + col] = __float2bfloat16(o);
            }
        }
}

// ---------------------------------------------------------------------------
// Kernel 3: relu(agg @ W3 + b3) . W4 -> atomicAdd into out.
// r11: LDS-traffic-optimized. 256x256 block tile, 4 waves (2x2), wave tile
// 128x128, ONE block per CU (grid 256, LDS 128 KB, 1 wave/SIMD, 512-VGPR
// budget). Per K-tile per CU: 64 KB frag reads + 32 KB staging = 96 KB
// (r8 was 256 KB with 2 blocks) -> LDS floor ~750-1030 cyc vs MFMA 621.
// Frag double-buffer across tile parity (fits at 1 wave/SIMD: ~420 regs).
// vmcnt ledger: 8 stage ops/tile; end-of-tile vmcnt(8) certifies buffer
// tt+2; prefetch at tile tt reads buffer tt+1 (certified one barrier ago).
// ---------------------------------------------------------------------------
#define NT 128   // K-tiles of 32

__global__ __launch_bounds__(256, 1) void gemm3_kernel(
    const __hip_bfloat16* __restrict__ agg,   // [16384][4096]
    const __hip_bfloat16* __restrict__ w3t,   // [1024][4096]
    const float* __restrict__ b3, const float* __restrict__ W4,
    float* __restrict__ out) {
    const int bid = ((blockIdx.x & 7) << 5) + (blockIdx.x >> 3);   // T1 swizzle
    const int brow = (bid >> 2) * 256;
    const int bcol = (bid & 3) * 256;
    const int t = threadIdx.x;
    const int lane = t & 63;
    const int wid = t >> 6;                   // 4 waves
    const int wm = wid >> 1, wn = wid & 1;    // 2 x 2, wave tile 128x128
    const int l15 = lane & 15, g = lane >> 4;

    // LDS: buffer pair p (p=0..3) at p*32768: A 16 KB @ +0, B 16 KB @ +16384
    __shared__ __align__(16) char smem[131072];

    // staging: thread t handles chunks t, t+256, t+512, t+768 (rows step 64);
    // dest linear, source col pre-swizzled (st_16x32; row bit3 indep. of j)
    const int r0 = t >> 2;
    const int col0 = ((t & 3) * 8) ^ ((r0 & 8) ? 16 : 0);
    const __hip_bfloat16* aSrc = agg + (size_t)(brow + r0) * KDIM + col0;
    const __hip_bfloat16* bSrc = w3t + (size_t)(bcol + r0) * KDIM + col0;

#define STAGE_AB(p, kt) do { \
        gload_lds16(aSrc + (size_t)(kt) * 32,                  smem + (p) * 32768 + t * 16); \
        gload_lds16(aSrc + (size_t)(kt) * 32 +  64 * KDIM,     smem + (p) * 32768 + t * 16 + 4096); \
        gload_lds16(aSrc + (size_t)(kt) * 32 + 128 * KDIM,     smem + (p) * 32768 + t * 16 + 8192); \
        gload_lds16(aSrc + (size_t)(kt) * 32 + 192 * KDIM,     smem + (p) * 32768 + t * 16 + 12288); \
        gload_lds16(bSrc + (size_t)(kt) * 32,                  smem + (p) * 32768 + 16384 + t * 16); \
        gload_lds16(bSrc + (size_t)(kt) * 32 +  64 * KDIM,     smem + (p) * 32768 + 16384 + t * 16 + 4096); \
        gload_lds16(bSrc + (size_t)(kt) * 32 + 128 * KDIM,     smem + (p) * 32768 + 16384 + t * 16 + 8192); \
        gload_lds16(bSrc + (size_t)(kt) * 32 + 192 * KDIM,     smem + (p) * 32768 + 16384 + t * 16 + 12288); } while (0)

    // swizzled fragment reads (row&8 == l15&8 for all m/n)
    const int coff = (g * 16) ^ ((l15 & 8) ? 32 : 0);
    const int aBase = (wm * 128 + l15) * 64 + coff;
    const int bBase = 16384 + (wn * 128 + l15) * 64 + coff;

#define LDFRAGS(FA, FB, p) do { \
        FA[0] = *(const short8*)(smem + (p) * 32768 + aBase + 0 * 1024); \
        FA[1] = *(const short8*)(smem + (p) * 32768 + aBase + 1 * 1024); \
        FA[2] = *(const short8*)(smem + (p) * 32768 + aBase + 2 * 1024); \
        FA[3] = *(const short8*)(smem + (p) * 32768 + aBase + 3 * 1024); \
        FA[4] = *(const short8*)(smem + (p) * 32768 + aBase + 4 * 1024); \
        FA[5] = *(const short8*)(smem + (p) * 32768 + aBase + 5 * 1024); \
        FA[6] = *(const short8*)(smem + (p) * 32768 + aBase + 6 * 1024); \
        FA[7] = *(const short8*)(smem + (p) * 32768 + aBase + 7 * 1024); \
        FB[0] = *(const short8*)(smem + (p) * 32768 + bBase + 0 * 1024); \
        FB[1] = *(const short8*)(smem + (p) * 32768 + bBase + 1 * 1024); \
        FB[2] = *(const short8*)(smem + (p) * 32768 + bBase + 2 * 1024); \
        FB[3] = *(const short8*)(smem + (p) * 32768 + bBase + 3 * 1024); \
        FB[4] = *(const short8*)(smem + (p) * 32768 + bBase + 4 * 1024); \
        FB[5] = *(const short8*)(smem + (p) * 32768 + bBase + 5 * 1024); \
        FB[6] = *(const short8*)(smem + (p) * 32768 + bBase + 6 * 1024); \
        FB[7] = *(const short8*)(smem + (p) * 32768 + bBase + 7 * 1024); } while (0)

#define MM(FA, FB) do { \
        __builtin_amdgcn_s_setprio(1); \
        _Pragma("unroll") \
        for (int mm = 0; mm < 8; mm++) \
            _Pragma("unroll") \
            for (int nn = 0; nn < 8; nn++) \
                acc[mm][nn] = __builtin_amdgcn_mfma_f32_16x16x32_bf16( \
                    FA[mm], FB[nn], acc[mm][nn], 0, 0, 0); \
        __builtin_amdgcn_s_setprio(0); } while (0)

#define TILE(FAc, FBc, FAn, FBn, pn, DOPREF, DOSTAGE, kt3, VMSTR) do { \
        if (DOPREF) LDFRAGS(FAn, FBn, pn); \
        if (DOSTAGE) STAGE_AB((kt3) & 3, kt3); \
        MM(FAc, FBc); \
        asm volatile(VMSTR ::: "memory"); \
        __builtin_amdgcn_s_barrier(); \
        __builtin_amdgcn_sched_barrier(0); } while (0)

    short8 faA[8], fbA[8], faB[8], fbB[8];
    f32x4 acc[8][8];
#pragma unroll
    for (int m = 0; m < 8; m++)
#pragma unroll
        for (int n = 0; n < 8; n++) acc[m][n] = (f32x4){0.f, 0.f, 0.f, 0.f};

    // prologue: stage tiles 0,1,2 (24 vm ops); vmcnt(8) certifies buf0,buf1
    // (leaves stage2's 8 ops); barrier; read tile0 frags.
    STAGE_AB(0, 0);
    STAGE_AB(1, 1);
    STAGE_AB(2, 2);
    asm volatile("s_waitcnt vmcnt(8)" ::: "memory");
    __builtin_amdgcn_s_barrier();
    __builtin_amdgcn_sched_barrier(0);
    LDFRAGS(faA, fbA, 0);

    // main loop: tiles 0..123 in parity pairs; stages 3..126
    for (int t2 = 0; t2 < 62; ++t2) {
        const int tt = t2 * 2;
        TILE(faA, fbA, faB, fbB, (tt + 1) & 3, 1, 1, tt + 3, "s_waitcnt vmcnt(8)");
        TILE(faB, fbB, faA, fbA, (tt + 2) & 3, 1, 1, tt + 4, "s_waitcnt vmcnt(8)");
    }
    // tail: 124 (stages 127), 125, 126, 127
    TILE(faA, fbA, faB, fbB, 1, 1, 1, 127, "s_waitcnt vmcnt(8)");
    TILE(faB, fbB, faA, fbA, 2, 1, 0, 0,   "s_waitcnt vmcnt(0)");
    TILE(faA, fbA, faB, fbB, 3, 1, 0, 0,   "s_waitcnt vmcnt(0)");
    MM(faB, fbB);

    // epilogue: bias+relu, dot W4, 16-lane reduce, atomicAdd per row
    float bias[8], w4v[8];
#pragma unroll
    for (int n = 0; n < 8; n++) {
        int col = bcol + wn * 128 + n * 16 + l15;
        bias[n] = b3[col];
        w4v[n] = W4[col];
    }
#pragma unroll
    for (int m = 0; m < 8; m++) {
        float pr0 = 0.f, pr1 = 0.f, pr2 = 0.f, pr3 = 0.f;
#pragma unroll
        for (int n = 0; n < 8; n++) {
            pr0 += fmaxf(acc[m][n][0] + bias[n], 0.f) * w4v[n];
            pr1 += fmaxf(acc[m][n][1] + bias[n], 0.f) * w4v[n];
            pr2 += fmaxf(acc[m][n][2] + bias[n], 0.f) * w4v[n];
            pr3 += fmaxf(acc[m][n][3] + bias[n], 0.f) * w4v[n];
        }
#pragma unroll
        for (int mask = 1; mask < 16; mask <<= 1) {
            pr0 += __shfl_xor(pr0, mask, 64);
            pr1 += __shfl_xor(pr1, mask, 64);
            pr2 += __shfl_xor(pr2, mask, 64);
            pr3 += __shfl_xor(pr3, mask, 64);
        }
        if (l15 == 0) {
            int row = brow + wm * 128 + m * 16 + g * 4;
            atomicAdd(&out[row + 0], pr0);
            atomicAdd(&out[row + 1], pr1);
            atomicAdd(&out[row + 2], pr2);
            atomicAdd(&out[row + 3], pr3);
        }
    }
}

// ---------------------------------------------------------------------------
extern "C" void kernel_launch(void* const* d_in, const int* in_sizes, int n_in,
                              void* d_out, int out_size, void* d_ws, size_t ws_size,
                              hipStream_t stream) {
    const float* inputs = (const float*)d_in[0];
    const float* W1 = (const float*)d_in[1];
    const float* b1 = (const float*)d_in[2];
    const float* W2 = (const float*)d_in[3];
    const float* b2 = (const float*)d_in[4];
    const float* imp = (const float*)d_in[5];
    const float* W3 = (const float*)d_in[6];
    const float* b3 = (const float*)d_in[7];
    const float* W4 = (const float*)d_in[8];
    const float* b4 = (const float*)d_in[9];
    float* out = (float*)d_out;

    char* ws = (char*)d_ws;
    const size_t agg_bytes = (size_t)B_ROWS * KDIM * 2;        // 134 MB
    const size_t w3t_bytes = (size_t)H2 * KDIM * 2;            // 8.4 MB
    const size_t w1b_bytes = (size_t)NVARS * 64 * 40 * 2;
    const size_t w2b_bytes = (size_t)NVARS * 64 * 72 * 2;

    __hip_bfloat16* agg = (__hip_bfloat16*)ws;
    __hip_bfloat16* w3t = (__hip_bfloat16*)(ws + agg_bytes);
    short* w1bh = (short*)(ws + agg_bytes + w3t_bytes);
    short* w1bl = (short*)(ws + agg_bytes + w3t_bytes + w1b_bytes);
    short* w2bh = (short*)(ws + agg_bytes + w3t_bytes + 2 * w1b_bytes);
    short* w2bl = (short*)(ws + agg_bytes + w3t_bytes + 2 * w1b_bytes + w2b_bytes);

    hipLaunchKernelGGL(misc_pre_kernel, dim3(1152), dim3(256), 0, stream,
                       W3, b4, W1, W2, w3t, out, w1bh, w1bl, w2bh, w2bl);
    hipLaunchKernelGGL(subnets_mfma_kernel, dim3(NVARS * (B_ROWS / 128)), dim3(256), 0, stream,
                       inputs, b1, b2, imp, w1bh, w1bl, w2bh, w2bl, agg);
    hipLaunchKernelGGL(gemm3_kernel, dim3((B_ROWS / 256) * (H2 / 256)), dim3(256), 0, stream,
                       agg, w3t, b3, W4, out);
}

// Round 12
// 163.646 us; speedup vs baseline: 1.3677x; 1.1200x over previous
//
#include <hip/hip_runtime.h>
#include <hip/hip_bf16.h>
#include <stdint.h>

#define B_ROWS 16384
#define NVARS 64
#define LAG 16
#define H1 64
#define H2 1024
#define KDIM (NVARS * H1)   // 4096

typedef __attribute__((ext_vector_type(8))) short short8;
typedef __attribute__((ext_vector_type(4))) short short4v;
typedef __attribute__((ext_vector_type(4))) float f32x4;

typedef __attribute__((address_space(3))) uint8_t lds_u8;
typedef const __attribute__((address_space(1))) uint8_t glob_u8;

__device__ __forceinline__ void gload_lds16(const void* g, void* l) {
    __builtin_amdgcn_global_load_lds((glob_u8*)g, (lds_u8*)l, 16, 0, 0);
}

__device__ __forceinline__ short f2bf_s(float x) {
    __hip_bfloat16 h = __float2bfloat16(x);
    return *(short*)&h;
}
__device__ __forceinline__ float bf_s2f(short s) {
    __hip_bfloat16 h = *(__hip_bfloat16*)&s;
    return __bfloat162float(h);
}

// ---------------------------------------------------------------------------
// Kernel 1: per-var W1/W2 -> hi/lo B-operand prep (64 blocks, global writes)
// ---------------------------------------------------------------------------
__global__ __launch_bounds__(256) void prep_w12_kernel(
    const float* __restrict__ W1, const float* __restrict__ W2,
    short* __restrict__ w1bh, short* __restrict__ w1bl,
    short* __restrict__ w2bh, short* __restrict__ w2bl) {
    const int v = blockIdx.x, t = threadIdx.x;
    for (int idx = t; idx < 64 * 32; idx += 256) {
        int col = idx >> 5, k = idx & 31;
        float wv = W1[((size_t)v * LAG + (k & 15)) * H1 + col];
        short hi = f2bf_s(wv);
        w1bh[((size_t)v * 64 + col) * 40 + k] = hi;
        w1bl[((size_t)v * 64 + col) * 40 + k] = (k < 16) ? f2bf_s(wv - bf_s2f(hi)) : (short)0;
    }
    for (int idx = t; idx < 64 * 64; idx += 256) {
        int col = idx >> 6, k = idx & 63;
        float wv = W2[((size_t)v * H1 + k) * H1 + col];
        short hi = f2bf_s(wv);
        w2bh[((size_t)v * 64 + col) * 72 + k] = hi;
        w2bl[((size_t)v * 64 + col) * 72 + k] = f2bf_s(wv - bf_s2f(hi));
    }
}

// ---------------------------------------------------------------------------
// Kernel 2 (fused): [0,1024) W3 transpose->bf16 | [1024,1088) out=b4 |
//                   [1088,9280) subnets (r8-validated body, untouched)
// ---------------------------------------------------------------------------
__global__ __launch_bounds__(256) void subnets_fused_kernel(
    const float* __restrict__ inputs, const float* __restrict__ b1g,
    const float* __restrict__ b2g, const float* __restrict__ impg,
    const short* __restrict__ w1bh_g, const short* __restrict__ w1bl_g,
    const short* __restrict__ w2bh_g, const short* __restrict__ w2bl_g,
    const float* __restrict__ w3, const float* __restrict__ b4,
    __hip_bfloat16* __restrict__ w3t, float* __restrict__ out,
    __hip_bfloat16* __restrict__ agg) {
    __shared__ __align__(16) char smem[38912];
    const int bid = blockIdx.x;
    const int t = threadIdx.x;

    if (bid < 1024) {
        float (*tile)[65] = (float (*)[65])smem;
        const int k0 = (bid >> 4) * 64;
        const int n0 = (bid & 15) * 64;
        const int c = t & 63, r0 = t >> 6;
#pragma unroll
        for (int i = 0; i < 16; i++) {
            int r = r0 + i * 4;
            tile[r][c] = w3[(size_t)(k0 + r) * H2 + n0 + c];
        }
        __syncthreads();
#pragma unroll
        for (int i = 0; i < 16; i++) {
            int nr = r0 + i * 4;
            w3t[(size_t)(n0 + nr) * KDIM + k0 + c] = __float2bfloat16(tile[c][nr]);
        }
        return;
    }
    if (bid < 1088) {
        out[(bid - 1024) * 256 + t] = b4[0];
        return;
    }

    const int sbid = bid - 1088;
    const int v = sbid >> 7;
    const int b0 = (sbid & 127) * 128;
    const int lane = t & 63, wv = t >> 6;
    const int l15 = lane & 15, g = lane >> 4;

    short* xsS   = (short*)smem;
    short* w1bhS = (short*)(smem + 10240);
    short* w1blS = (short*)(smem + 15360);
    short* Hs    = (short*)smem;
    short* w2bhS = (short*)(smem + 20480);
    short* w2blS = (short*)(smem + 29696);

    for (int c = t; c < 320; c += 256) {
        gload_lds16(w1bh_g + (size_t)v * 2560 + c * 8, (char*)w1bhS + c * 16);
        gload_lds16(w1bl_g + (size_t)v * 2560 + c * 8, (char*)w1blS + c * 16);
    }
    for (int c = t; c < 576; c += 256) {
        gload_lds16(w2bh_g + (size_t)v * 4608 + c * 8, (char*)w2bhS + c * 16);
        gload_lds16(w2bl_g + (size_t)v * 4608 + c * 8, (char*)w2blS + c * 16);
    }
#pragma unroll
    for (int i = 0; i < 2; i++) {
        int idx = t + i * 256;
        int row = idx >> 2, seg = idx & 3;
        float4 x4 = *(const float4*)(inputs + (size_t)(b0 + row) * (NVARS * LAG) + v * LAG + seg * 4);
        const float* xp = (const float*)&x4;
        short4v hv, lv;
#pragma unroll
        for (int j = 0; j < 4; j++) {
            short hi = f2bf_s(xp[j]);
            hv[j] = hi;
            lv[j] = f2bf_s(xp[j] - bf_s2f(hi));
        }
        *(short4v*)&xsS[row * 40 + seg * 4] = hv;
        *(short4v*)&xsS[row * 40 + 16 + seg * 4] = lv;
    }
    __syncthreads();

    short8 a1[2], b1hF[4], b1lF[4];
#pragma unroll
    for (int mt = 0; mt < 2; mt++)
        a1[mt] = *(const short8*)&xsS[(wv * 32 + mt * 16 + l15) * 40 + g * 8];
#pragma unroll
    for (int nt = 0; nt < 4; nt++) {
        b1hF[nt] = *(const short8*)&w1bhS[(nt * 16 + l15) * 40 + g * 8];
        b1lF[nt] = *(const short8*)&w1blS[(nt * 16 + l15) * 40 + g * 8];
    }
    f32x4 acc1[2][4];
#pragma unroll
    for (int mt = 0; mt < 2; mt++)
#pragma unroll
        for (int nt = 0; nt < 4; nt++) {
            acc1[mt][nt] = (f32x4){0.f, 0.f, 0.f, 0.f};
            acc1[mt][nt] = __builtin_amdgcn_mfma_f32_16x16x32_bf16(a1[mt], b1hF[nt], acc1[mt][nt], 0, 0, 0);
            acc1[mt][nt] = __builtin_amdgcn_mfma_f32_16x16x32_bf16(a1[mt], b1lF[nt], acc1[mt][nt], 0, 0, 0);
        }
    __syncthreads();

#pragma unroll
    for (int mt = 0; mt < 2; mt++)
#pragma unroll
        for (int nt = 0; nt < 4; nt++) {
            int col = nt * 16 + l15;
            float bias = b1g[v * H1 + col];
#pragma unroll
            for (int r = 0; r < 4; r++) {
                float h = fmaxf(acc1[mt][nt][r] + bias, 0.f);
                int row = wv * 32 + mt * 16 + g * 4 + r;
                Hs[row * 72 + col] = f2bf_s(h);
            }
        }
    __syncthreads();

    short8 a2[2][2], b2hF[4][2], b2lF[4][2];
#pragma unroll
    for (int mt = 0; mt < 2; mt++)
#pragma unroll
        for (int kc = 0; kc < 2; kc++)
            a2[mt][kc] = *(const short8*)&Hs[(wv * 32 + mt * 16 + l15) * 72 + kc * 32 + g * 8];
#pragma unroll
    for (int nt = 0; nt < 4; nt++)
#pragma unroll
        for (int kc = 0; kc < 2; kc++) {
            b2hF[nt][kc] = *(const short8*)&w2bhS[(nt * 16 + l15) * 72 + kc * 32 + g * 8];
            b2lF[nt][kc] = *(const short8*)&w2blS[(nt * 16 + l15) * 72 + kc * 32 + g * 8];
        }
    f32x4 acc2[2][4];
#pragma unroll
    for (int mt = 0; mt < 2; mt++)
#pragma unroll
        for (int nt = 0; nt < 4; nt++) {
            f32x4 a = (f32x4){0.f, 0.f, 0.f, 0.f};
            a = __builtin_amdgcn_mfma_f32_16x16x32_bf16(a2[mt][0], b2hF[nt][0], a, 0, 0, 0);
            a = __builtin_amdgcn_mfma_f32_16x16x32_bf16(a2[mt][1], b2hF[nt][1], a, 0, 0, 0);
            a = __builtin_amdgcn_mfma_f32_16x16x32_bf16(a2[mt][0], b2lF[nt][0], a, 0, 0, 0);
            a = __builtin_amdgcn_mfma_f32_16x16x32_bf16(a2[mt][1], b2lF[nt][1], a, 0, 0, 0);
            acc2[mt][nt] = a;
        }

    const float impv = impg[v];
#pragma unroll
    for (int mt = 0; mt < 2; mt++)
#pragma unroll
        for (int nt = 0; nt < 4; nt++) {
            int col = nt * 16 + l15;
            float bias = b2g[v * H1 + col];
#pragma unroll
            for (int r = 0; r < 4; r++) {
                float o = fmaxf(acc2[mt][nt][r] + bias, 0.f) * impv;
                int row = b0 + wv * 32 + mt * 16 + g * 4 + r;
                agg[(size_t)row * KDIM + v * H1 + col] = __float2bfloat16(o);
            }
        }
}

// ---------------------------------------------------------------------------
// Kernel 3: relu(agg @ W3 + b3) . W4 -> atomicAdd into out.
// r12: faithful m201 8-phase schedule. BK=64 (2 K-steps/iter = 128 K), 8
// waves (2Mx4N), 512 thr. LDS = 2 dbufs x {Ak0,Ak1,Bk0,Bk1} 16-KB regions
// (each [256 rows][32 cols], r8-proven swizzle: src-preswizzled stage +
// coff-XOR read). Per phase: {4-8 ds_reads | 2 gload_lds staging the region
// freed exactly one phase earlier | barrier | lgkmcnt(0)+sched_barrier |
// setprio(1) 16 MFMA setprio(0) | barrier}; vmcnt(6) only at phases 4 & 8.
// B-frags loaded once per k32, reused across both m-half phases.
// Stage ledger per iter i (regions freed at prior phase, kt in 32-units):
//  ph0:D1A1<-4i+3  ph1:D0B0<-4i+4  ph2:D0A0<-4i+4  ph3:D0B1<-4i+5
//  ph4:D0A1<-4i+5  ph5:D1B0<-4i+6  ph6:D1A0<-4i+6  ph7:D1B1<-4i+7
// Certification: region staged at ph p is consumed >=4 phases later; the
// vmcnt(6) every 4 phases leaves only the newest 3 stages outstanding.
// ---------------------------------------------------------------------------
#define D0A0 0
#define D0A1 16384
#define D0B0 32768
#define D0B1 49152
#define D1A0 65536
#define D1A1 81920
#define D1B0 98304
#define D1B1 114688

__global__ __launch_bounds__(512, 2) void gemm3_kernel(
    const __hip_bfloat16* __restrict__ agg,   // [16384][4096]
    const __hip_bfloat16* __restrict__ w3t,   // [1024][4096]
    const float* __restrict__ b3, const float* __restrict__ W4,
    float* __restrict__ out) {
    const int bid = ((blockIdx.x & 7) << 5) + (blockIdx.x >> 3);   // T1 swizzle
    const int brow = (bid >> 2) * 256;
    const int bcol = (bid & 3) * 256;
    const int t = threadIdx.x;
    const int lane = t & 63;
    const int wid = t >> 6;                   // 8 waves
    const int wm = wid >> 2, wn = wid & 3;    // 2 x 4, wave tile 128x64
    const int l15 = lane & 15, g = lane >> 4;

    __shared__ __align__(16) char smem[131072];

    // staging: chunk c -> region byte c*16 (linear); source col pre-swizzled
    const int c0 = t, c1 = t + 512;
    const int r0 = c0 >> 2, r1 = c1 >> 2;
    const int col0 = ((c0 & 3) * 8) ^ ((r0 & 8) ? 16 : 0);
    const int col1 = ((c1 & 3) * 8) ^ ((r1 & 8) ? 16 : 0);
    const __hip_bfloat16* aS0 = agg + (size_t)(brow + r0) * KDIM + col0;
    const __hip_bfloat16* aS1 = agg + (size_t)(brow + r1) * KDIM + col1;
    const __hip_bfloat16* bS0 = w3t + (size_t)(bcol + r0) * KDIM + col0;
    const __hip_bfloat16* bS1 = w3t + (size_t)(bcol + r1) * KDIM + col1;

#define SA(rb, kt) do { \
        gload_lds16(aS0 + (size_t)(kt) * 32, smem + (rb) + c0 * 16); \
        gload_lds16(aS1 + (size_t)(kt) * 32, smem + (rb) + c1 * 16); } while (0)
#define SB(rb, kt) do { \
        gload_lds16(bS0 + (size_t)(kt) * 32, smem + (rb) + c0 * 16); \
        gload_lds16(bS1 + (size_t)(kt) * 32, smem + (rb) + c1 * 16); } while (0)

    // swizzled fragment reads within a 16-KB region ([256 rows][32 cols])
    const int coff = (g * 16) ^ ((l15 & 8) ? 32 : 0);
    const int aBase = (wm * 128 + l15) * 64 + coff;
    const int bBase = (wn * 64 + l15) * 64 + coff;

#define LDA4(rb, MH) do { \
        fa[0] = *(const short8*)(smem + (rb) + aBase + ((MH) * 4 + 0) * 1024); \
        fa[1] = *(const short8*)(smem + (rb) + aBase + ((MH) * 4 + 1) * 1024); \
        fa[2] = *(const short8*)(smem + (rb) + aBase + ((MH) * 4 + 2) * 1024); \
        fa[3] = *(const short8*)(smem + (rb) + aBase + ((MH) * 4 + 3) * 1024); } while (0)
#define LDB4(FB, rb) do { \
        FB[0] = *(const short8*)(smem + (rb) + bBase + 0 * 1024); \
        FB[1] = *(const short8*)(smem + (rb) + bBase + 1 * 1024); \
        FB[2] = *(const short8*)(smem + (rb) + bBase + 2 * 1024); \
        FB[3] = *(const short8*)(smem + (rb) + bBase + 3 * 1024); } while (0)

#define MFMA16(MH, FB) \
        _Pragma("unroll") \
        for (int mm = 0; mm < 4; mm++) { \
            _Pragma("unroll") \
            for (int nn = 0; nn < 4; nn++) \
                acc[(MH) * 4 + mm][nn] = __builtin_amdgcn_mfma_f32_16x16x32_bf16( \
                    fa[mm], FB[nn], acc[(MH) * 4 + mm][nn], 0, 0, 0); \
        }

#define PHX(MH, FB) do { \
        __builtin_amdgcn_s_barrier(); \
        asm volatile("s_waitcnt lgkmcnt(0)" ::: "memory"); \
        __builtin_amdgcn_sched_barrier(0); \
        __builtin_amdgcn_s_setprio(1); \
        MFMA16(MH, FB) \
        __builtin_amdgcn_s_setprio(0); \
        __builtin_amdgcn_s_barrier(); } while (0)

#define PHXV(MH, FB, VM) do { \
        __builtin_amdgcn_s_barrier(); \
        asm volatile("s_waitcnt lgkmcnt(0)" ::: "memory"); \
        __builtin_amdgcn_sched_barrier(0); \
        __builtin_amdgcn_s_setprio(1); \
        MFMA16(MH, FB) \
        __builtin_amdgcn_s_setprio(0); \
        asm volatile(VM ::: "memory"); \
        __builtin_amdgcn_s_barrier(); } while (0)

    short8 fa[4], fbk0[4], fbk1[4];
    f32x4 acc[8][4];
#pragma unroll
    for (int m = 0; m < 8; m++)
#pragma unroll
        for (int n = 0; n < 4; n++) acc[m][n] = (f32x4){0.f, 0.f, 0.f, 0.f};

    // prologue: dbuf0 fully (kt 0,1), dbuf1 minus Ak1 (kt 2,3) = 14 gloads;
    // vmcnt(6) drains the 8 dbuf0 gloads; barrier.
    SA(D0A0, 0); SA(D0A1, 1); SB(D0B0, 0); SB(D0B1, 1);
    SA(D1A0, 2); SB(D1B0, 2); SB(D1B1, 3);
    asm volatile("s_waitcnt vmcnt(6)" ::: "memory");
    __builtin_amdgcn_s_barrier();
    __builtin_amdgcn_sched_barrier(0);

    // main loop: iters 0..30 (steps 2i,2i+1; stages per ledger above)
    for (int i = 0; i < 31; ++i) {
        const int k4 = i * 4;
        LDB4(fbk0, D0B0); LDA4(D0A0, 0); SA(D1A1, k4 + 3);  PHX(0, fbk0);
        LDA4(D0A0, 1);    SB(D0B0, k4 + 4);                 PHX(1, fbk0);
        LDB4(fbk1, D0B1); LDA4(D0A1, 0); SA(D0A0, k4 + 4);  PHX(0, fbk1);
        LDA4(D0A1, 1);    SB(D0B1, k4 + 5);                 PHXV(1, fbk1, "s_waitcnt vmcnt(6)");
        LDB4(fbk0, D1B0); LDA4(D1A0, 0); SA(D0A1, k4 + 5);  PHX(0, fbk0);
        LDA4(D1A0, 1);    SB(D1B0, k4 + 6);                 PHX(1, fbk0);
        LDB4(fbk1, D1B1); LDA4(D1A1, 0); SA(D1A0, k4 + 6);  PHX(0, fbk1);
        LDA4(D1A1, 1);    SB(D1B1, k4 + 7);                 PHXV(1, fbk1, "s_waitcnt vmcnt(6)");
    }
    // peeled final iter (steps 62,63): only ph0 stages (D1A1 <- kt 127);
    // ph3 drains everything (vmcnt 0) so ph4-7 reads are certified.
    LDB4(fbk0, D0B0); LDA4(D0A0, 0); SA(D1A1, 127);         PHX(0, fbk0);
    LDA4(D0A0, 1);                                          PHX(1, fbk0);
    LDB4(fbk1, D0B1); LDA4(D0A1, 0);                        PHX(0, fbk1);
    LDA4(D0A1, 1);                                          PHXV(1, fbk1, "s_waitcnt vmcnt(0)");
    LDB4(fbk0, D1B0); LDA4(D1A0, 0);                        PHX(0, fbk0);
    LDA4(D1A0, 1);                                          PHX(1, fbk0);
    LDB4(fbk1, D1B1); LDA4(D1A1, 0);                        PHX(0, fbk1);
    LDA4(D1A1, 1);                                          PHX(1, fbk1);

    // epilogue: bias+relu, dot W4, 16-lane reduce, atomicAdd per row
    float bias[4], w4v[4];
#pragma unroll
    for (int n = 0; n < 4; n++) {
        int col = bcol + wn * 64 + n * 16 + l15;
        bias[n] = b3[col];
        w4v[n] = W4[col];
    }
#pragma unroll
    for (int m = 0; m < 8; m++) {
        float pr0 = 0.f, pr1 = 0.f, pr2 = 0.f, pr3 = 0.f;
#pragma unroll
        for (int n = 0; n < 4; n++) {
            pr0 += fmaxf(acc[m][n][0] + bias[n], 0.f) * w4v[n];
            pr1 += fmaxf(acc[m][n][1] + bias[n], 0.f) * w4v[n];
            pr2 += fmaxf(acc[m][n][2] + bias[n], 0.f) * w4v[n];
            pr3 += fmaxf(acc[m][n][3] + bias[n], 0.f) * w4v[n];
        }
#pragma unroll
        for (int mask = 1; mask < 16; mask <<= 1) {
            pr0 += __shfl_xor(pr0, mask, 64);
            pr1 += __shfl_xor(pr1, mask, 64);
            pr2 += __shfl_xor(pr2, mask, 64);
            pr3 += __shfl_xor(pr3, mask, 64);
        }
        if (l15 == 0) {
            int row = brow + wm * 128 + m * 16 + g * 4;
            atomicAdd(&out[row + 0], pr0);
            atomicAdd(&out[row + 1], pr1);
            atomicAdd(&out[row + 2], pr2);
            atomicAdd(&out[row + 3], pr3);
        }
    }
}

// ---------------------------------------------------------------------------
extern "C" void kernel_launch(void* const* d_in, const int* in_sizes, int n_in,
                              void* d_out, int out_size, void* d_ws, size_t ws_size,
                              hipStream_t stream) {
    const float* inputs = (const float*)d_in[0];
    const float* W1 = (const float*)d_in[1];
    const float* b1 = (const float*)d_in[2];
    const float* W2 = (const float*)d_in[3];
    const float* b2 = (const float*)d_in[4];
    const float* imp = (const float*)d_in[5];
    const float* W3 = (const float*)d_in[6];
    const float* b3 = (const float*)d_in[7];
    const float* W4 = (const float*)d_in[8];
    const float* b4 = (const float*)d_in[9];
    float* out = (float*)d_out;

    char* ws = (char*)d_ws;
    const size_t agg_bytes = (size_t)B_ROWS * KDIM * 2;        // 134 MB
    const size_t w3t_bytes = (size_t)H2 * KDIM * 2;            // 8.4 MB
    const size_t w1b_bytes = (size_t)NVARS * 64 * 40 * 2;
    const size_t w2b_bytes = (size_t)NVARS * 64 * 72 * 2;

    __hip_bfloat16* agg = (__hip_bfloat16*)ws;
    __hip_bfloat16* w3t = (__hip_bfloat16*)(ws + agg_bytes);
    short* w1bh = (short*)(ws + agg_bytes + w3t_bytes);
    short* w1bl = (short*)(ws + agg_bytes + w3t_bytes + w1b_bytes);
    short* w2bh = (short*)(ws + agg_bytes + w3t_bytes + 2 * w1b_bytes);
    short* w2bl = (short*)(ws + agg_bytes + w3t_bytes + 2 * w1b_bytes + w2b_bytes);

    hipLaunchKernelGGL(prep_w12_kernel, dim3(NVARS), dim3(256), 0, stream,
                       W1, W2, w1bh, w1bl, w2bh, w2bl);
    hipLaunchKernelGGL(subnets_fused_kernel, dim3(1088 + NVARS * (B_ROWS / 128)), dim3(256), 0, stream,
                       inputs, b1, b2, imp, w1bh, w1bl, w2bh, w2bl,
                       W3, b4, w3t, out, agg);
    hipLaunchKernelGGL(gemm3_kernel, dim3((B_ROWS / 256) * (H2 / 256)), dim3(512), 0, stream,
                       agg, w3t, b3, W4, out);
}